// Round 11
// baseline (642.161 us; speedup 1.0000x reference)
//
#include <hip/hip_runtime.h>
#include <hip/hip_fp16.h>
#include <math.h>

#define NN 100000
#define NE 1600000
#define NBKT 391                       // ceil(NN/256) buckets of 256 nodes
#define CHUNK 8192
#define NB1 ((NE + CHUNK - 1) / CHUNK) // 196 blocks
#define SEGS 8                         // src-octile count
#define QSEG 12500                     // octile width: 8 slices x 1.6 MB fp16
#define NNP (NN + 8)                   // padded stride for seg arrays
#define CAP 5120                       // fixed bucket capacity (mean 4096, sigma ~64; +16 sigma)

typedef _Float16 v8h __attribute__((ext_vector_type(8)));
typedef float v4f __attribute__((ext_vector_type(4)));
typedef unsigned int v4u __attribute__((ext_vector_type(4)));

union H4 { uint2 u; __half2 h[2]; };

// ---------- phase 1: scatter packed (src<<8 | dst&255) into fixed-capacity bucket runs ----------
__global__ __launch_bounds__(256) void p1_scatter_kernel(const int* __restrict__ src,
                                                         const int* __restrict__ dst,
                                                         int* __restrict__ bcnt,
                                                         int* __restrict__ gpair) {
    __shared__ int h[NBKT], rb[NBKT], hc[NBKT];
    int tid = threadIdx.x;
    for (int b = tid; b < NBKT; b += 256) { h[b] = 0; hc[b] = 0; }
    __syncthreads();
    int e0 = blockIdx.x * CHUNK;
    for (int k = 0; k < CHUNK / 256; ++k) {
        int e = e0 + tid + k * 256;
        if (e < NE) atomicAdd(&h[dst[e] >> 8], 1);
    }
    __syncthreads();
    for (int b = tid; b < NBKT; b += 256)
        rb[b] = h[b] ? atomicAdd(&bcnt[b], h[b]) : 0;   // reserve block-private run
    __syncthreads();
    for (int k = 0; k < CHUNK / 256; ++k) {
        int e = e0 + tid + k * 256;
        if (e < NE) {
            int d = dst[e], s = src[e];
            int b = d >> 8;
            int pos = b * CAP + rb[b] + atomicAdd(&hc[b], 1);
            gpair[pos] = (s << 8) | (d & 255);
        }
    }
}

// ---------- phase 2: per-bucket place -> csr (src-octile-partitioned), seg[9], nrm ----------
// + fused input scale: x' = fp16(x * nrm) -> hA for this block's 256 nodes.
__global__ __launch_bounds__(256) void p2_place_kernel(const int* __restrict__ gpair,
                                                       const int* __restrict__ bcnt,
                                                       int* __restrict__ csr,
                                                       int* __restrict__ seg,
                                                       float* __restrict__ nrm,
                                                       const float4* __restrict__ x4,
                                                       uint2* __restrict__ xs) {
    __shared__ int cseg[SEGS][256], nexcl[256], sb[SEGS][256], pq[SEGS][256];
    __shared__ float nrmS[256];
    int b = blockIdx.x, tid = threadIdx.x;
    int s0 = b * CAP, s1 = s0 + bcnt[b];
#pragma unroll
    for (int q = 0; q < SEGS; ++q) { cseg[q][tid] = 0; pq[q][tid] = 0; }
    __syncthreads();
    for (int i = s0 + tid; i < s1; i += 256) {
        int p = gpair[i];
        int l = p & 255;
        int q = (p >> 8) / QSEG;
        atomicAdd(&cseg[q][l], 1);
    }
    __syncthreads();
    int v = 0;
#pragma unroll
    for (int q = 0; q < SEGS; ++q) v += cseg[q][tid];
    nexcl[tid] = v;
    __syncthreads();
    for (int off = 1; off < 256; off <<= 1) {
        int t = (tid >= off) ? nexcl[tid - off] : 0;
        __syncthreads();
        nexcl[tid] += t;
        __syncthreads();
    }
    int ex = nexcl[tid] - v;                 // exclusive within bucket
    int base = s0 + ex;                      // csr window shares b*CAP layout
    int node = (b << 8) + tid;
    float nv = rsqrtf(fmaxf((float)v, 1.0f));
    {
        int run = base;
#pragma unroll
        for (int q = 0; q < SEGS; ++q) {
            if (node < NN) seg[q * NNP + node] = run;
            sb[q][tid] = run;
            run += cseg[q][tid];
        }
        if (node < NN) { seg[SEGS * NNP + node] = run; nrm[node] = nv; }
    }
    nrmS[tid] = nv;
    __syncthreads();
    for (int i = s0 + tid; i < s1; i += 256) {
        int p = gpair[i];
        int l = p & 255;
        int s = p >> 8;
        int q = s / QSEG;
        int pos = sb[q][l] + atomicAdd(&pq[q][l], 1);
        csr[pos] = s;                        // block-owned contiguous window
    }
    // ---- fused scale: x' = fp16(x * nrm) for this block's nodes ----
    int nbase = b << 8;
    int nvalid = NN - nbase; if (nvalid > 256) nvalid = 256;
    for (int idx = tid; idx < nvalid * 16; idx += 256) {
        int nl = idx >> 4, f = idx & 15;
        float s = nrmS[nl];
        float4 xv = x4[(size_t)(nbase + nl) * 16 + f];
        H4 w;
        w.h[0] = __floats2half2_rn(xv.x * s, xv.y * s);
        w.h[1] = __floats2half2_rn(xv.z * s, xv.w * s);
        xs[(size_t)(nbase + nl) * 16 + f] = w.u;
    }
}

// ---------------- fused layer: gather8 (R8-proven loop, 8 passes) + MFMA apply ----------------
// Phase A: 8 src-octile passes (1.6 MB slices: half of R8's L2 footprint -> fewer evictions).
// Phase B: fp16 agg -> padded LDS; per-wave MFMA; epilogue -> padded LDS -> nt coop stores
//   (write-once streams bypass L2 -> stop evicting the slice; loads stay cached — R9 lesson).
// W split hi/lo fp16 (two MFMA accums) => effective ~fp32 weights.
// Layouts (m89-verified): A row=lane&15, k=(lane>>4)*8+j ; C/D col=lane&15, row=(lane>>4)*4+reg.
template<int IN, int ACT, bool SCALE, bool DUAL>
__global__ __launch_bounds__(256) void gcn_layer_kernel(
        const __half* __restrict__ h,
        const float* __restrict__ nrm,
        const int* __restrict__ seg,          // [SEGS+1][NNP]
        const int* __restrict__ csr,
        const float* __restrict__ Wa, const float* __restrict__ ba,
        const float* __restrict__ Wb, const float* __restrict__ bb,
        void* __restrict__ outv, float* __restrict__ out2,
        const float* __restrict__ eps, __half* __restrict__ zbuf) {
    constexpr int MLP = 8;
    constexpr int RL  = IN / 4;        // lanes per row
    constexpr int EPI = 64 / RL;       // edges per iteration per node
    constexpr int KH  = IN / 32;       // K halves of 32
    constexpr int AS  = IN + 8;        // agg LDS stride (halves)
    constexpr int HS  = 72;            // fp16 out stride (halves)
    constexpr int FS  = 68;            // fp32 out stride (floats)
    constexpr int MS  = 36;            // mu/lv stride (floats)
    constexpr int OUTB = DUAL ? (2 * 32 * MS * 4) : (SCALE ? 32 * HS * 2 : 32 * FS * 4);
    __shared__ __half aggH[32 * AS];
    __shared__ __align__(16) char smem[OUTB];

    int tid = threadIdx.x;
    int wave = tid >> 6, lane = tid & 63;
    int row_slot = lane / RL;
    int f4 = lane % RL;
    int nodeBase = (blockIdx.x * 4 + wave) * MLP;   // 32 nodes/block, grid 3125 exact
    const uint2* hp = (const uint2*)h;

    // ======== phase A: gather (R8-proven: cached csr, plain loads; 8 octile passes) ========
    float4 acc[MLP];
#pragma unroll
    for (int i = 0; i < MLP; ++i) acc[i] = make_float4(0.f, 0.f, 0.f, 0.f);

    int cur[MLP];
#pragma unroll
    for (int i = 0; i < MLP; ++i) cur[i] = seg[nodeBase + i];

    for (int q = 0; q < SEGS; ++q) {
        int nxt[MLP];
#pragma unroll
        for (int i = 0; i < MLP; ++i) nxt[i] = seg[(q + 1) * NNP + nodeBase + i];
        int maxd = 0;
#pragma unroll
        for (int i = 0; i < MLP; ++i) maxd = max(maxd, nxt[i] - cur[i]);

        for (int t = 0; t < maxd; t += EPI) {
            int s[MLP]; float m[MLP];
#pragma unroll
            for (int i = 0; i < MLP; ++i) {             // batch: all csr loads (cached)
                int jj = cur[i] + t + row_slot;
                bool ok = jj < nxt[i];
                s[i] = csr[ok ? jj : 0];
                m[i] = ok ? 1.f : 0.f;
            }
            H4 v[MLP];
#pragma unroll
            for (int i = 0; i < MLP; ++i)               // batch: all row loads (L2 slice)
                v[i].u = hp[(size_t)s[i] * RL + f4];
#pragma unroll
            for (int i = 0; i < MLP; ++i) {             // math
                float2 f01 = __half22float2(v[i].h[0]);
                float2 f23 = __half22float2(v[i].h[1]);
                acc[i].x = fmaf(m[i], f01.x, acc[i].x);
                acc[i].y = fmaf(m[i], f01.y, acc[i].y);
                acc[i].z = fmaf(m[i], f23.x, acc[i].z);
                acc[i].w = fmaf(m[i], f23.y, acc[i].w);
            }
        }
#pragma unroll
        for (int i = 0; i < MLP; ++i) cur[i] = nxt[i];
    }

#pragma unroll
    for (int i = 0; i < MLP; ++i) {
        for (int o = RL; o < 64; o <<= 1) {
            acc[i].x += __shfl_xor(acc[i].x, o);
            acc[i].y += __shfl_xor(acc[i].y, o);
            acc[i].z += __shfl_xor(acc[i].z, o);
            acc[i].w += __shfl_xor(acc[i].w, o);
        }
    }

    // fp16 agg -> LDS (same rounding as old pAgg path)
    if (row_slot == 0) {
#pragma unroll
        for (int i = 0; i < MLP; ++i) {
            H4 w;
            w.h[0] = __floats2half2_rn(acc[i].x, acc[i].y);
            w.h[1] = __floats2half2_rn(acc[i].z, acc[i].w);
            *(uint2*)&aggH[(wave * MLP + i) * AS + f4 * 4] = w.u;
        }
    }

    // ======== W fragments (latency overlaps the barrier) ========
    int col = lane & 15, kgrp = lane >> 4;
    v8h Bhi[KH], Blo[KH];
    float bias;
    {
        const float* wrow;
        if (DUAL) wrow = (wave < 2) ? (Wa + (size_t)(wave * 16 + col) * 64)
                                    : (Wb + (size_t)((wave - 2) * 16 + col) * 64);
        else      wrow = Wa + (size_t)(wave * 16 + col) * IN;
        bias = DUAL ? ((wave < 2) ? ba[wave * 16 + col] : bb[(wave - 2) * 16 + col])
                    : ba[wave * 16 + col];
#pragma unroll
        for (int kh = 0; kh < KH; ++kh) {
            const float* wp = wrow + kh * 32 + kgrp * 8;
            float4 w0 = *(const float4*)(wp);
            float4 w1 = *(const float4*)(wp + 4);
            float wv[8] = {w0.x, w0.y, w0.z, w0.w, w1.x, w1.y, w1.z, w1.w};
#pragma unroll
            for (int j = 0; j < 8; ++j) {
                _Float16 hv = (_Float16)wv[j];
                Bhi[kh][j] = hv;
                Blo[kh][j] = (_Float16)(wv[j] - (float)hv);
            }
        }
    }
    __syncthreads();

    // ======== phase B: MFMA apply (wave owns out cols wave*16..+15) ========
    v4f dacc[2];
#pragma unroll
    for (int a2 = 0; a2 < 2; ++a2) dacc[a2] = (v4f){0.f, 0.f, 0.f, 0.f};

#pragma unroll
    for (int a2 = 0; a2 < 2; ++a2) {
        int arow = a2 * 16 + col;                   // block-local node
#pragma unroll
        for (int kh = 0; kh < KH; ++kh) {
            v8h A = *(const v8h*)&aggH[arow * AS + kh * 32 + kgrp * 8];
            dacc[a2] = __builtin_amdgcn_mfma_f32_16x16x32_f16(A, Bhi[kh], dacc[a2], 0, 0, 0);
            dacc[a2] = __builtin_amdgcn_mfma_f32_16x16x32_f16(A, Blo[kh], dacc[a2], 0, 0, 0);
        }
    }

    // epilogue -> padded LDS
    float*  smu = (float*)smem;                 // DUAL: [32][MS]
    float*  slv = smu + 32 * MS;                // DUAL: [32][MS]
    __half* sh  = (__half*)smem;                // SCALE: [32][HS]
    float*  sf  = (float*)smem;                 // fp32:  [32][FS]
    size_t gbase = (size_t)blockIdx.x * 32;

#pragma unroll
    for (int a2 = 0; a2 < 2; ++a2) {
#pragma unroll
        for (int r = 0; r < 4; ++r) {
            int lnode = a2 * 16 + kgrp * 4 + r;
            float nv = nrm[gbase + lnode];
            float v = dacc[a2][r] * nv + bias;
            if (ACT == 1) v = fmaxf(v, 0.f);
            if (ACT == 2) v = 1.f / (1.f + expf(-v));
            if (DUAL) {
                if (wave < 2) smu[lnode * MS + wave * 16 + col] = v;
                else          slv[lnode * MS + (wave - 2) * 16 + col] = v;
            } else if (SCALE) {
                sh[lnode * HS + wave * 16 + col] = __float2half(v * nv);
            } else {
                sf[lnode * FS + wave * 16 + col] = v;
            }
        }
    }
    __syncthreads();

    // coop copy LDS -> global: write-once streams -> nontemporal stores (keep L2 for h)
    if (DUAL) {
        float* mu_p = (float*)outv;
        for (int idx = tid; idx < 32 * 8; idx += 256) {          // mu: 128 B/row
            int r = idx >> 3, c = idx & 7;
            v4u v = *(const v4u*)&smu[r * MS + c * 4];
            __builtin_nontemporal_store(v, (v4u*)(mu_p + (gbase + r) * 32) + c);
        }
        for (int idx = tid; idx < 32 * 8; idx += 256) {          // lv: 128 B/row
            int r = idx >> 3, c = idx & 7;
            v4u v = *(const v4u*)&slv[r * MS + c * 4];
            __builtin_nontemporal_store(v, (v4u*)(out2 + (gbase + r) * 32) + c);
        }
        for (int idx = tid; idx < 32 * 4; idx += 256) {          // z: fused reparam, 64 B/row
            int r = idx >> 2, c0 = (idx & 3) * 8;
            size_t node = gbase + r;
            float nv = nrm[node];
            float zv[8];
#pragma unroll
            for (int j = 0; j < 8; ++j) {
                float e  = eps[node * 32 + c0 + j];
                float mv = smu[r * MS + c0 + j];
                float lw = slv[r * MS + c0 + j];
                zv[j] = (e * expf(0.5f * lw) + mv) * nv;
            }
            H4 w0, w1;
            w0.h[0] = __floats2half2_rn(zv[0], zv[1]);
            w0.h[1] = __floats2half2_rn(zv[2], zv[3]);
            w1.h[0] = __floats2half2_rn(zv[4], zv[5]);
            w1.h[1] = __floats2half2_rn(zv[6], zv[7]);
            v4u o16;
            o16.x = w0.u.x; o16.y = w0.u.y; o16.z = w1.u.x; o16.w = w1.u.y;
            __builtin_nontemporal_store(o16, (v4u*)(zbuf + node * 32) + (c0 >> 3));
        }
    } else if (SCALE) {
        __half* hout = (__half*)outv;
        for (int idx = tid; idx < 32 * 8; idx += 256) {          // 128 B/row fp16
            int r = idx >> 3, c = idx & 7;
            v4u v = *(const v4u*)&sh[r * HS + c * 8];
            __builtin_nontemporal_store(v, (v4u*)(hout + (gbase + r) * 64) + c);
        }
    } else {
        float* fout = (float*)outv;
        for (int idx = tid; idx < 32 * 16; idx += 256) {         // 256 B/row fp32
            int r = idx >> 4, c = idx & 15;
            v4u v = *(const v4u*)&sf[r * FS + c * 4];
            __builtin_nontemporal_store(v, (v4u*)(fout + (gbase + r) * 64) + c);
        }
    }
}

extern "C" void kernel_launch(void* const* d_in, const int* in_sizes, int n_in,
                              void* d_out, int out_size, void* d_ws, size_t ws_size,
                              hipStream_t stream) {
    const float* x    = (const float*)d_in[0];
    const int*   esrc = (const int*)d_in[1];
    const int*   edst = (const int*)d_in[2];
    const float* eps  = (const float*)d_in[3];
    const float* W1  = (const float*)d_in[4];  const float* b1  = (const float*)d_in[5];
    const float* W2  = (const float*)d_in[6];  const float* b2  = (const float*)d_in[7];
    const float* W31 = (const float*)d_in[8];  const float* b31 = (const float*)d_in[9];
    const float* W32 = (const float*)d_in[10]; const float* b32 = (const float*)d_in[11];
    const float* W4  = (const float*)d_in[12]; const float* b4  = (const float*)d_in[13];
    const float* W5  = (const float*)d_in[14]; const float* b5  = (const float*)d_in[15];
    const float* W6  = (const float*)d_in[16]; const float* b6  = (const float*)d_in[17];

    float* outp  = (float*)d_out;
    float* recon = outp;                        // N*64
    float* mu    = outp + (size_t)NN * 64;      // N*32
    float* lv    = mu   + (size_t)NN * 32;      // N*32

    int* wsI       = (int*)d_ws;
    int* bcnt      = wsI;                       // 392 (global cursors)
    int* seg       = bcnt + 392;                // (SEGS+1)*NNP (octile starts + end)
    int* csr       = seg + (SEGS + 1) * NNP;    // NBKT*CAP (bucket windows)
    int* gpair     = csr + NBKT * CAP;          // NBKT*CAP
    float* nrm     = (float*)(gpair + NBKT * CAP); // NN
    __half* hA     = (__half*)(nrm + NN);       // NN*64 halves (12.8 MB), 16B-aligned
    __half* hB     = hA + (size_t)NN * 64;      // NN*64 halves

    const int fgrid = NN / 32;                  // 3125: 4 waves x 8 nodes, exact

    // ---- CSR build (fixed-capacity buckets) + fused x-scale ----
    hipMemsetAsync(bcnt, 0, 392 * sizeof(int), stream);
    p1_scatter_kernel<<<NB1, 256, 0, stream>>>(esrc, edst, bcnt, gpair);
    p2_place_kernel<<<NBKT, 256, 0, stream>>>(gpair, bcnt, csr, seg, nrm,
                                              (const float4*)x, (uint2*)hA);

    // ---- 6 fused layers (gather8 + MFMA apply each) ----
    // L1
    gcn_layer_kernel<64, 1, true,  false><<<fgrid, 256, 0, stream>>>(hA, nrm, seg, csr, W1,  b1,  nullptr, nullptr, hB,    nullptr, nullptr, nullptr);
    // L2
    gcn_layer_kernel<64, 1, true,  false><<<fgrid, 256, 0, stream>>>(hB, nrm, seg, csr, W2,  b2,  nullptr, nullptr, hA,    nullptr, nullptr, nullptr);
    // L3 dual: mu/lv -> d_out (fp32), fused z' -> hB (fp16, N*32)
    gcn_layer_kernel<64, 0, false, true ><<<fgrid, 256, 0, stream>>>(hA, nrm, seg, csr, W31, b31, W32,     b32,     mu,    lv,      eps,     hB);
    // L4 (IN=32)
    gcn_layer_kernel<32, 1, true,  false><<<fgrid, 256, 0, stream>>>(hB, nrm, seg, csr, W4,  b4,  nullptr, nullptr, hA,    nullptr, nullptr, nullptr);
    // L5
    gcn_layer_kernel<64, 1, true,  false><<<fgrid, 256, 0, stream>>>(hA, nrm, seg, csr, W5,  b5,  nullptr, nullptr, hB,    nullptr, nullptr, nullptr);
    // L6 (fp32 out, sigmoid)
    gcn_layer_kernel<64, 2, false, false><<<fgrid, 256, 0, stream>>>(hB, nrm, seg, csr, W6,  b6,  nullptr, nullptr, recon, nullptr, nullptr, nullptr);
}

// Round 12
// 536.009 us; speedup vs baseline: 1.1980x; 1.1980x over previous
//
#include <hip/hip_runtime.h>
#include <hip/hip_fp16.h>
#include <math.h>

#define NN 100000
#define NE 1600000
#define NBKT 391                       // ceil(NN/256) buckets of 256 nodes
#define CHUNK 8192
#define NB1 ((NE + CHUNK - 1) / CHUNK) // 196 blocks
#define QSEG 25000                     // src-quartile width: 4 slices x 3.2 MB fp16
#define NNP (NN + 8)                   // padded stride for seg arrays
#define CAP 5120                       // fixed bucket capacity (mean 4096, sigma ~64; +16 sigma)

typedef _Float16 v8h __attribute__((ext_vector_type(8)));
typedef float v4f __attribute__((ext_vector_type(4)));

union H4 { uint2 u; __half2 h[2]; };

// ---------- phase 1: scatter packed (src<<8 | dst&255) into fixed-capacity bucket runs ----------
// No p0/scan needed: bucket windows are b*CAP; bcnt acts as global per-bucket cursor (memset to 0).
__global__ __launch_bounds__(256) void p1_scatter_kernel(const int* __restrict__ src,
                                                         const int* __restrict__ dst,
                                                         int* __restrict__ bcnt,
                                                         int* __restrict__ gpair) {
    __shared__ int h[NBKT], rb[NBKT], hc[NBKT];
    int tid = threadIdx.x;
    for (int b = tid; b < NBKT; b += 256) { h[b] = 0; hc[b] = 0; }
    __syncthreads();
    int e0 = blockIdx.x * CHUNK;
    for (int k = 0; k < CHUNK / 256; ++k) {
        int e = e0 + tid + k * 256;
        if (e < NE) atomicAdd(&h[dst[e] >> 8], 1);
    }
    __syncthreads();
    for (int b = tid; b < NBKT; b += 256)
        rb[b] = h[b] ? atomicAdd(&bcnt[b], h[b]) : 0;   // reserve block-private run
    __syncthreads();
    for (int k = 0; k < CHUNK / 256; ++k) {
        int e = e0 + tid + k * 256;
        if (e < NE) {
            int d = dst[e], s = src[e];
            int b = d >> 8;
            int pos = b * CAP + rb[b] + atomicAdd(&hc[b], 1);
            gpair[pos] = (s << 8) | (d & 255);
        }
    }
}

// ---------- phase 2: per-bucket place -> csr (src-quartile-partitioned), seg[5], nrm ----------
// + fused input scale: x' = fp16(x * nrm) -> hA for this block's 256 nodes.
__global__ __launch_bounds__(256) void p2_place_kernel(const int* __restrict__ gpair,
                                                       const int* __restrict__ bcnt,
                                                       int* __restrict__ csr,
                                                       int* __restrict__ seg,
                                                       float* __restrict__ nrm,
                                                       const float4* __restrict__ x4,
                                                       uint2* __restrict__ xs) {
    __shared__ int cseg[4][256], nexcl[256], sb[4][256], pq[4][256];
    __shared__ float nrmS[256];
    int b = blockIdx.x, tid = threadIdx.x;
    int s0 = b * CAP, s1 = s0 + bcnt[b];
#pragma unroll
    for (int q = 0; q < 4; ++q) { cseg[q][tid] = 0; pq[q][tid] = 0; }
    __syncthreads();
    for (int i = s0 + tid; i < s1; i += 256) {
        int p = gpair[i];
        int l = p & 255;
        int q = (p >> 8) / QSEG;
        atomicAdd(&cseg[q][l], 1);
    }
    __syncthreads();
    int v = cseg[0][tid] + cseg[1][tid] + cseg[2][tid] + cseg[3][tid];
    nexcl[tid] = v;
    __syncthreads();
    for (int off = 1; off < 256; off <<= 1) {
        int t = (tid >= off) ? nexcl[tid - off] : 0;
        __syncthreads();
        nexcl[tid] += t;
        __syncthreads();
    }
    int ex = nexcl[tid] - v;                 // exclusive within bucket
    int base = s0 + ex;                      // csr window shares b*CAP layout
    int node = (b << 8) + tid;
    int c0 = cseg[0][tid], c1 = cseg[1][tid], c2 = cseg[2][tid];
    float nv = rsqrtf(fmaxf((float)v, 1.0f));
    if (node < NN) {
        seg[0 * NNP + node] = base;
        seg[1 * NNP + node] = base + c0;
        seg[2 * NNP + node] = base + c0 + c1;
        seg[3 * NNP + node] = base + c0 + c1 + c2;
        seg[4 * NNP + node] = base + v;
        nrm[node] = nv;
    }
    nrmS[tid] = nv;
    sb[0][tid] = base;
    sb[1][tid] = base + c0;
    sb[2][tid] = base + c0 + c1;
    sb[3][tid] = base + c0 + c1 + c2;
    __syncthreads();
    for (int i = s0 + tid; i < s1; i += 256) {
        int p = gpair[i];
        int l = p & 255;
        int s = p >> 8;
        int q = s / QSEG;
        int pos = sb[q][l] + atomicAdd(&pq[q][l], 1);
        csr[pos] = s;                        // block-owned contiguous window
    }
    // ---- fused scale: x' = fp16(x * nrm) for this block's nodes ----
    int nbase = b << 8;
    int nvalid = NN - nbase; if (nvalid > 256) nvalid = 256;
    for (int idx = tid; idx < nvalid * 16; idx += 256) {
        int nl = idx >> 4, f = idx & 15;
        float s = nrmS[nl];
        float4 xv = x4[(size_t)(nbase + nl) * 16 + f];
        H4 w;
        w.h[0] = __floats2half2_rn(xv.x * s, xv.y * s);
        w.h[1] = __floats2half2_rn(xv.z * s, xv.w * s);
        xs[(size_t)(nbase + nl) * 16 + f] = w.u;
    }
}

// ---------------- fused layer: gather4 (R5-proven loop) + MFMA apply, one launch ----------------
// Phase A: 4 src-quartile passes (3.2 MB slices, L2-resident), acc in registers.
// Phase B: fp16 agg -> padded LDS [32][IN+8]; per-wave MFMA (wave owns 16 out cols);
//          epilogue staged in padded LDS; coalesced coop copy to global (CACHED stores:
//          hA/hB are re-read next layer through L2/L3 — nt stores cost 2.2->1.75 TB/s, R11).
// W split hi/lo fp16 (two MFMA accums) => effective ~fp32 weights.
// Layouts (m89-verified): A row=lane&15, k=(lane>>4)*8+j ; C/D col=lane&15, row=(lane>>4)*4+reg.
template<int IN, int ACT, bool SCALE, bool DUAL>
__global__ __launch_bounds__(256) void gcn_layer_kernel(
        const __half* __restrict__ h,
        const float* __restrict__ nrm,
        const int* __restrict__ seg,          // [5][NNP]
        const int* __restrict__ csr,
        const float* __restrict__ Wa, const float* __restrict__ ba,
        const float* __restrict__ Wb, const float* __restrict__ bb,
        void* __restrict__ outv, float* __restrict__ out2,
        const float* __restrict__ eps, __half* __restrict__ zbuf) {
    constexpr int MLP = 8;
    constexpr int RL  = IN / 4;        // lanes per row
    constexpr int EPI = 64 / RL;       // edges per iteration per node
    constexpr int KH  = IN / 32;       // K halves of 32 (2 for IN=64, 1 for IN=32)
    constexpr int AS  = IN + 8;        // agg LDS stride (halves): <=2-way banks
    constexpr int HS  = 72;            // fp16 out stride (halves)
    constexpr int FS  = 68;            // fp32 out stride (floats)
    constexpr int MS  = 36;            // mu/lv stride (floats)
    constexpr int OUTB = DUAL ? (2 * 32 * MS * 4) : (SCALE ? 32 * HS * 2 : 32 * FS * 4);
    __shared__ __half aggH[32 * AS];
    __shared__ __align__(16) char smem[OUTB];

    int tid = threadIdx.x;
    int wave = tid >> 6, lane = tid & 63;
    int row_slot = lane / RL;
    int f4 = lane % RL;
    int nodeBase = (blockIdx.x * 4 + wave) * MLP;   // 32 nodes/block, grid 3125 exact
    const uint2* hp = (const uint2*)h;

    // ======== phase A: gather (R5-proven: cached csr, plain loads) ========
    float4 acc[MLP];
#pragma unroll
    for (int i = 0; i < MLP; ++i) acc[i] = make_float4(0.f, 0.f, 0.f, 0.f);

    int cur[MLP];
#pragma unroll
    for (int i = 0; i < MLP; ++i) cur[i] = seg[nodeBase + i];

    for (int q = 0; q < 4; ++q) {
        int nxt[MLP];
#pragma unroll
        for (int i = 0; i < MLP; ++i) nxt[i] = seg[(q + 1) * NNP + nodeBase + i];
        int maxd = 0;
#pragma unroll
        for (int i = 0; i < MLP; ++i) maxd = max(maxd, nxt[i] - cur[i]);

        for (int t = 0; t < maxd; t += EPI) {
            int s[MLP]; float m[MLP];
#pragma unroll
            for (int i = 0; i < MLP; ++i) {             // batch: all csr loads (cached)
                int jj = cur[i] + t + row_slot;
                bool ok = jj < nxt[i];
                s[i] = csr[ok ? jj : 0];
                m[i] = ok ? 1.f : 0.f;
            }
            H4 v[MLP];
#pragma unroll
            for (int i = 0; i < MLP; ++i)               // batch: all row loads (L2 slice)
                v[i].u = hp[(size_t)s[i] * RL + f4];
#pragma unroll
            for (int i = 0; i < MLP; ++i) {             // math
                float2 f01 = __half22float2(v[i].h[0]);
                float2 f23 = __half22float2(v[i].h[1]);
                acc[i].x = fmaf(m[i], f01.x, acc[i].x);
                acc[i].y = fmaf(m[i], f01.y, acc[i].y);
                acc[i].z = fmaf(m[i], f23.x, acc[i].z);
                acc[i].w = fmaf(m[i], f23.y, acc[i].w);
            }
        }
#pragma unroll
        for (int i = 0; i < MLP; ++i) cur[i] = nxt[i];
    }

#pragma unroll
    for (int i = 0; i < MLP; ++i) {
        for (int o = RL; o < 64; o <<= 1) {
            acc[i].x += __shfl_xor(acc[i].x, o);
            acc[i].y += __shfl_xor(acc[i].y, o);
            acc[i].z += __shfl_xor(acc[i].z, o);
            acc[i].w += __shfl_xor(acc[i].w, o);
        }
    }

    // fp16 agg -> LDS (same rounding as old pAgg path)
    if (row_slot == 0) {
#pragma unroll
        for (int i = 0; i < MLP; ++i) {
            H4 w;
            w.h[0] = __floats2half2_rn(acc[i].x, acc[i].y);
            w.h[1] = __floats2half2_rn(acc[i].z, acc[i].w);
            *(uint2*)&aggH[(wave * MLP + i) * AS + f4 * 4] = w.u;
        }
    }

    // ======== W fragments (latency overlaps the barrier) ========
    int col = lane & 15, kgrp = lane >> 4;
    v8h Bhi[KH], Blo[KH];
    float bias;
    {
        const float* wrow;
        if (DUAL) wrow = (wave < 2) ? (Wa + (size_t)(wave * 16 + col) * 64)
                                    : (Wb + (size_t)((wave - 2) * 16 + col) * 64);
        else      wrow = Wa + (size_t)(wave * 16 + col) * IN;
        bias = DUAL ? ((wave < 2) ? ba[wave * 16 + col] : bb[(wave - 2) * 16 + col])
                    : ba[wave * 16 + col];
#pragma unroll
        for (int kh = 0; kh < KH; ++kh) {
            const float* wp = wrow + kh * 32 + kgrp * 8;
            float4 w0 = *(const float4*)(wp);
            float4 w1 = *(const float4*)(wp + 4);
            float wv[8] = {w0.x, w0.y, w0.z, w0.w, w1.x, w1.y, w1.z, w1.w};
#pragma unroll
            for (int j = 0; j < 8; ++j) {
                _Float16 hv = (_Float16)wv[j];
                Bhi[kh][j] = hv;
                Blo[kh][j] = (_Float16)(wv[j] - (float)hv);
            }
        }
    }
    __syncthreads();

    // ======== phase B: MFMA apply (wave owns out cols wave*16..+15) ========
    v4f dacc[2];
#pragma unroll
    for (int a2 = 0; a2 < 2; ++a2) dacc[a2] = (v4f){0.f, 0.f, 0.f, 0.f};

#pragma unroll
    for (int a2 = 0; a2 < 2; ++a2) {
        int arow = a2 * 16 + col;                   // block-local node
#pragma unroll
        for (int kh = 0; kh < KH; ++kh) {
            v8h A = *(const v8h*)&aggH[arow * AS + kh * 32 + kgrp * 8];
            dacc[a2] = __builtin_amdgcn_mfma_f32_16x16x32_f16(A, Bhi[kh], dacc[a2], 0, 0, 0);
            dacc[a2] = __builtin_amdgcn_mfma_f32_16x16x32_f16(A, Blo[kh], dacc[a2], 0, 0, 0);
        }
    }

    // epilogue -> padded LDS
    float*  smu = (float*)smem;                 // DUAL: [32][MS]
    float*  slv = smu + 32 * MS;                // DUAL: [32][MS]
    __half* sh  = (__half*)smem;                // SCALE: [32][HS]
    float*  sf  = (float*)smem;                 // fp32:  [32][FS]
    size_t gbase = (size_t)blockIdx.x * 32;

#pragma unroll
    for (int a2 = 0; a2 < 2; ++a2) {
#pragma unroll
        for (int r = 0; r < 4; ++r) {
            int lnode = a2 * 16 + kgrp * 4 + r;
            float nv = nrm[gbase + lnode];
            float v = dacc[a2][r] * nv + bias;
            if (ACT == 1) v = fmaxf(v, 0.f);
            if (ACT == 2) v = 1.f / (1.f + expf(-v));
            if (DUAL) {
                if (wave < 2) smu[lnode * MS + wave * 16 + col] = v;
                else          slv[lnode * MS + (wave - 2) * 16 + col] = v;
            } else if (SCALE) {
                sh[lnode * HS + wave * 16 + col] = __float2half(v * nv);
            } else {
                sf[lnode * FS + wave * 16 + col] = v;
            }
        }
    }
    __syncthreads();

    // coop copy LDS -> global (coalesced 16-B CACHED stores); grid covers NN exactly
    if (DUAL) {
        float* mu_p = (float*)outv;
        for (int idx = tid; idx < 32 * 8; idx += 256) {          // mu: 128 B/row
            int r = idx >> 3, c = idx & 7;
            *((uint4*)(mu_p + (gbase + r) * 32) + c) = *(const uint4*)&smu[r * MS + c * 4];
        }
        for (int idx = tid; idx < 32 * 8; idx += 256) {          // lv: 128 B/row
            int r = idx >> 3, c = idx & 7;
            *((uint4*)(out2 + (gbase + r) * 32) + c) = *(const uint4*)&slv[r * MS + c * 4];
        }
        for (int idx = tid; idx < 32 * 4; idx += 256) {          // z: fused reparam, 64 B/row
            int r = idx >> 2, c0 = (idx & 3) * 8;
            size_t node = gbase + r;
            float nv = nrm[node];
            H4 w0, w1;
            float zv[8];
#pragma unroll
            for (int j = 0; j < 8; ++j) {
                float e  = eps[node * 32 + c0 + j];
                float mv = smu[r * MS + c0 + j];
                float lw = slv[r * MS + c0 + j];
                zv[j] = (e * expf(0.5f * lw) + mv) * nv;
            }
            w0.h[0] = __floats2half2_rn(zv[0], zv[1]);
            w0.h[1] = __floats2half2_rn(zv[2], zv[3]);
            w1.h[0] = __floats2half2_rn(zv[4], zv[5]);
            w1.h[1] = __floats2half2_rn(zv[6], zv[7]);
            uint4 out16;
            out16.x = w0.u.x; out16.y = w0.u.y; out16.z = w1.u.x; out16.w = w1.u.y;
            *((uint4*)(zbuf + node * 32) + (c0 >> 3)) = out16;
        }
    } else if (SCALE) {
        __half* hout = (__half*)outv;
        for (int idx = tid; idx < 32 * 8; idx += 256) {          // 128 B/row fp16
            int r = idx >> 3, c = idx & 7;
            *((uint4*)(hout + (gbase + r) * 64) + c) = *(const uint4*)&sh[r * HS + c * 8];
        }
    } else {
        float* fout = (float*)outv;
        for (int idx = tid; idx < 32 * 16; idx += 256) {         // 256 B/row fp32
            int r = idx >> 4, c = idx & 15;
            *((uint4*)(fout + (gbase + r) * 64) + c) = *(const uint4*)&sf[r * FS + c * 4];
        }
    }
}

extern "C" void kernel_launch(void* const* d_in, const int* in_sizes, int n_in,
                              void* d_out, int out_size, void* d_ws, size_t ws_size,
                              hipStream_t stream) {
    const float* x    = (const float*)d_in[0];
    const int*   esrc = (const int*)d_in[1];
    const int*   edst = (const int*)d_in[2];
    const float* eps  = (const float*)d_in[3];
    const float* W1  = (const float*)d_in[4];  const float* b1  = (const float*)d_in[5];
    const float* W2  = (const float*)d_in[6];  const float* b2  = (const float*)d_in[7];
    const float* W31 = (const float*)d_in[8];  const float* b31 = (const float*)d_in[9];
    const float* W32 = (const float*)d_in[10]; const float* b32 = (const float*)d_in[11];
    const float* W4  = (const float*)d_in[12]; const float* b4  = (const float*)d_in[13];
    const float* W5  = (const float*)d_in[14]; const float* b5  = (const float*)d_in[15];
    const float* W6  = (const float*)d_in[16]; const float* b6  = (const float*)d_in[17];

    float* outp  = (float*)d_out;
    float* recon = outp;                        // N*64
    float* mu    = outp + (size_t)NN * 64;      // N*32
    float* lv    = mu   + (size_t)NN * 32;      // N*32

    int* wsI       = (int*)d_ws;
    int* bcnt      = wsI;                       // 392 (global cursors)
    int* seg       = bcnt + 392;                // 5*NNP (quartile starts + end)
    int* csr       = seg + 5 * NNP;             // NBKT*CAP (bucket windows)
    int* gpair     = csr + NBKT * CAP;          // NBKT*CAP
    float* nrm     = (float*)(gpair + NBKT * CAP); // NN
    __half* hA     = (__half*)(nrm + NN);       // NN*64 halves (12.8 MB), 16B-aligned
    __half* hB     = hA + (size_t)NN * 64;      // NN*64 halves

    const int fgrid = NN / 32;                  // 3125: 4 waves x 8 nodes, exact

    // ---- CSR build (fixed-capacity buckets; no hist/scan passes) + fused x-scale ----
    hipMemsetAsync(bcnt, 0, 392 * sizeof(int), stream);
    p1_scatter_kernel<<<NB1, 256, 0, stream>>>(esrc, edst, bcnt, gpair);
    p2_place_kernel<<<NBKT, 256, 0, stream>>>(gpair, bcnt, csr, seg, nrm,
                                              (const float4*)x, (uint2*)hA);

    // ---- 6 fused layers (gather4 + MFMA apply each) ----
    // L1
    gcn_layer_kernel<64, 1, true,  false><<<fgrid, 256, 0, stream>>>(hA, nrm, seg, csr, W1,  b1,  nullptr, nullptr, hB,    nullptr, nullptr, nullptr);
    // L2
    gcn_layer_kernel<64, 1, true,  false><<<fgrid, 256, 0, stream>>>(hB, nrm, seg, csr, W2,  b2,  nullptr, nullptr, hA,    nullptr, nullptr, nullptr);
    // L3 dual: mu/lv -> d_out (fp32), fused z' -> hB (fp16, N*32)
    gcn_layer_kernel<64, 0, false, true ><<<fgrid, 256, 0, stream>>>(hA, nrm, seg, csr, W31, b31, W32,     b32,     mu,    lv,      eps,     hB);
    // L4 (IN=32)
    gcn_layer_kernel<32, 1, true,  false><<<fgrid, 256, 0, stream>>>(hB, nrm, seg, csr, W4,  b4,  nullptr, nullptr, hA,    nullptr, nullptr, nullptr);
    // L5
    gcn_layer_kernel<64, 1, true,  false><<<fgrid, 256, 0, stream>>>(hA, nrm, seg, csr, W5,  b5,  nullptr, nullptr, hB,    nullptr, nullptr, nullptr);
    // L6 (fp32 out, sigmoid)
    gcn_layer_kernel<64, 2, false, false><<<fgrid, 256, 0, stream>>>(hB, nrm, seg, csr, W6,  b6,  nullptr, nullptr, recon, nullptr, nullptr, nullptr);
}